// Round 11
// baseline (223.461 us; speedup 1.0000x reference)
//
#include <hip/hip_runtime.h>

// Problem constants: B=8, L=1024, H=512, F=4
// out = gate * [x | alpha @ x],  gate = sigmoid([x|enc] @ W_gate)
// alpha = masked_softmax(max_f(Y_f Y_f^T)),  Y = relu(x @ W_proj)
//
// Round 11: proj/gate -> BK=32 double-buffered (32 KB LDS -> 5 blocks/CU =
// 20 waves/CU, proj single dispatch round). r10 counters: proj 42 us with
// MfmaUtil/VALU/HBM all ~15% at 8 waves/CU -- same latency-bound signature
// score had before its 16-wave fix. Keeps 64x64 wave tile (low LDS/FLOP).
// Score/attn/softmax/prep unchanged from r10.

typedef _Float16 half8 __attribute__((ext_vector_type(8)));
typedef float floatx4 __attribute__((ext_vector_type(4)));

typedef const __attribute__((address_space(1))) void* gas_ptr;
typedef __attribute__((address_space(3))) void* las_ptr;

// ---- staging machinery, BK=64 rows (64 fp16/row, XOR-swizzle by row&7) ----

template<int NCH, int NT>
__device__ __forceinline__ void init_ptrs(const _Float16* src, int row0, int ld,
                                          const _Float16* gp[NCH]) {
  int t = threadIdx.x;
#pragma unroll
  for (int p = 0; p < NCH; ++p) {
    int c = p * NT + t;
    int row = c >> 3;
    int kg = c & 7;
    int gk = (kg ^ (row & 7)) << 3;
    gp[p] = src + (size_t)(row0 + row) * ld + gk;
  }
}

// ---- staging machinery, BK=32 rows (32 fp16/row, XOR-swizzle by row&3) ----

template<int NCH, int NT>
__device__ __forceinline__ void init_ptrs32(const _Float16* src, int row0, int ld,
                                            const _Float16* gp[NCH]) {
  int t = threadIdx.x;
#pragma unroll
  for (int p = 0; p < NCH; ++p) {
    int c = p * NT + t;
    int row = c >> 2;
    int kg = c & 3;
    int gk = (kg ^ (row & 3)) << 3;
    gp[p] = src + (size_t)(row0 + row) * ld + gk;
  }
}

// shared: LDS dst = chunk*16 B (wave-uniform base + lane*16 contract)
template<int NCH, int NT>
__device__ __forceinline__ void stage(const _Float16* const gp[NCH], _Float16* ldsbuf) {
  int t = threadIdx.x;
#pragma unroll
  for (int p = 0; p < NCH; ++p)
    __builtin_amdgcn_global_load_lds((gas_ptr)gp[p],
                                     (las_ptr)(ldsbuf + t * 8 + p * NT * 8), 16, 0, 0);
}

template<int NCH>
__device__ __forceinline__ void bump(const _Float16* gp[NCH], int d) {
#pragma unroll
  for (int p = 0; p < NCH; ++p) gp[p] += d;
}

__device__ __forceinline__ half8 frag_ld(const _Float16* lds, int row, int g) {
  return *(const half8*)(lds + row * 64 + ((g ^ (row & 7)) << 3));
}

__device__ __forceinline__ half8 frag_ld32(const _Float16* lds, int row, int g) {
  return *(const half8*)(lds + row * 32 + ((g ^ (row & 3)) << 3));
}

// 4-wave (2x2) block, BK=32 step: one k-fragment per step, 16 MFMA
__device__ __forceinline__ void mfma_tile44_32(const _Float16* la, const _Float16* lb,
                                               floatx4 acc[4][4], int wm, int wn,
                                               int l16, int quad) {
  half8 af[4], bf[4];
#pragma unroll
  for (int i = 0; i < 4; ++i) af[i] = frag_ld32(la, wm * 64 + i * 16 + l16, quad);
#pragma unroll
  for (int i = 0; i < 4; ++i) bf[i] = frag_ld32(lb, wn * 64 + i * 16 + l16, quad);
#pragma unroll
  for (int mi = 0; mi < 4; ++mi)
#pragma unroll
    for (int ni = 0; ni < 4; ++ni)
      acc[mi][ni] = __builtin_amdgcn_mfma_f32_16x16x32_f16(af[mi], bf[ni], acc[mi][ni], 0, 0, 0);
}

#define ZERO_ACC44(acc)                                 \
  _Pragma("unroll") for (int mi = 0; mi < 4; ++mi)      \
  _Pragma("unroll") for (int ni = 0; ni < 4; ++ni)      \
  _Pragma("unroll") for (int r = 0; r < 4; ++r) acc[mi][ni][r] = 0.0f;

// 8-wave (2x4) block, BK=64 step (score)
__device__ __forceinline__ void mfma_tile42(const _Float16* la, const _Float16* lb,
                                            floatx4 acc[4][2], int wm, int wn,
                                            int l16, int quad) {
#pragma unroll
  for (int kf = 0; kf < 2; ++kf) {
    half8 af[4], bf[2];
#pragma unroll
    for (int i = 0; i < 4; ++i) af[i] = frag_ld(la, wm * 64 + i * 16 + l16, kf * 4 + quad);
#pragma unroll
    for (int i = 0; i < 2; ++i) bf[i] = frag_ld(lb, wn * 32 + i * 16 + l16, kf * 4 + quad);
#pragma unroll
    for (int mi = 0; mi < 4; ++mi)
#pragma unroll
      for (int ni = 0; ni < 2; ++ni)
        acc[mi][ni] = __builtin_amdgcn_mfma_f32_16x16x32_f16(af[mi], bf[ni], acc[mi][ni], 0, 0, 0);
  }
}

#define ZERO_ACC42(acc)                                 \
  _Pragma("unroll") for (int mi = 0; mi < 4; ++mi)      \
  _Pragma("unroll") for (int ni = 0; ni < 2; ++ni)      \
  _Pragma("unroll") for (int r = 0; r < 4; ++r) acc[mi][ni][r] = 0.0f;

// ---- pre-pass ----

__global__ void x_prep_kernel(const float* __restrict__ in, _Float16* __restrict__ x16,
                              _Float16* __restrict__ xT) {
  __shared__ float tile[32][33];
  const int R = 1024, C = 512;
  int c0 = blockIdx.x * 32, r0 = blockIdx.y * 32;
  size_t boff = (size_t)blockIdx.z * R * C;
  in += boff; x16 += boff; xT += boff;
  int tx = threadIdx.x & 31, ty = threadIdx.x >> 5;  // 32 x 8
#pragma unroll
  for (int i = 0; i < 32; i += 8) {
    float v = in[(size_t)(r0 + ty + i) * C + c0 + tx];
    tile[ty + i][tx] = v;
    x16[(size_t)(r0 + ty + i) * C + c0 + tx] = (_Float16)v;
  }
  __syncthreads();
#pragma unroll
  for (int i = 0; i < 32; i += 8)
    xT[(size_t)(c0 + ty + i) * R + r0 + tx] = (_Float16)tile[tx][ty + i];
}

__global__ void w_prep_kernel(const float* __restrict__ Wp, _Float16* __restrict__ WpT,
                              const float* __restrict__ Wg, _Float16* __restrict__ WgT) {
  __shared__ float tile[32][33];
  const float* in; _Float16* out; int R, C, c0, r0;
  if (blockIdx.z == 0) {
    in = Wp; out = WpT; R = 512; C = 2048;
    c0 = blockIdx.x * 32; r0 = blockIdx.y * 32;
  } else {
    in = Wg; out = WgT; R = 1024; C = 1024;
    c0 = (blockIdx.x & 31) * 32; r0 = (blockIdx.y * 2 + (blockIdx.x >> 5)) * 32;
  }
  int tx = threadIdx.x & 31, ty = threadIdx.x >> 5;
#pragma unroll
  for (int i = 0; i < 32; i += 8)
    tile[ty + i][tx] = in[(size_t)(r0 + ty + i) * C + c0 + tx];
  __syncthreads();
#pragma unroll
  for (int i = 0; i < 32; i += 8)
    out[(size_t)(c0 + ty + i) * R + r0 + tx] = (_Float16)tile[tx][ty + i];
}

// ---- K1: y = relu(x @ W_proj + b_proj) -> y_t (B,F,L,H) fp16 ----
// 256 thr, 2x2 waves, 128x128 tile, dbuf BK=32: LDS 32 KB -> 5 blocks/CU
// (20 waves/CU), grid 1024 = single dispatch round. M=8192 N=2048 K=512.

__global__ __launch_bounds__(256) void proj_kernel(const _Float16* __restrict__ x16,
                                                   const _Float16* __restrict__ WpT,
                                                   const float* __restrict__ bp,
                                                   _Float16* __restrict__ y_t) {
  __shared__ __align__(16) _Float16 ldsA[2][128 * 32];
  __shared__ __align__(16) _Float16 ldsB[2][128 * 32];
  int i0 = blockIdx.x * 128, n0 = blockIdx.y * 128;
  int t = threadIdx.x, lane = t & 63, w = t >> 6;
  int wm = w >> 1, wn = w & 1, quad = lane >> 4, l16 = lane & 15;
  const _Float16* gpA[2]; const _Float16* gpB[2];
  init_ptrs32<2, 256>(x16, i0, 512, gpA);
  init_ptrs32<2, 256>(WpT, n0, 512, gpB);
  floatx4 acc[4][4];
  ZERO_ACC44(acc);
  stage<2, 256>(gpA, ldsA[0]); bump<2>(gpA, 32);
  stage<2, 256>(gpB, ldsB[0]); bump<2>(gpB, 32);
#pragma unroll 1
  for (int kt = 0; kt < 16; ++kt) {
    __syncthreads();
    if (kt < 15) {
      stage<2, 256>(gpA, ldsA[(kt + 1) & 1]); bump<2>(gpA, 32);
      stage<2, 256>(gpB, ldsB[(kt + 1) & 1]); bump<2>(gpB, 32);
    }
    mfma_tile44_32(ldsA[kt & 1], ldsB[kt & 1], acc, wm, wn, l16, quad);
  }
#pragma unroll
  for (int mi = 0; mi < 4; ++mi)
#pragma unroll
    for (int ni = 0; ni < 4; ++ni)
#pragma unroll
      for (int r = 0; r < 4; ++r) {
        int gr = i0 + wm * 64 + mi * 16 + quad * 4 + r;   // 0..8191
        int gc = n0 + wn * 64 + ni * 16 + l16;            // 0..2047
        float c = fmaxf(acc[mi][ni][r] + bp[gc], 0.0f);
        int b = gr >> 10, l = gr & 1023;
        int f = gc & 3, h = gc >> 2;
        y_t[(((size_t)(b * 4 + f)) * 1024 + l) * 512 + h] = (_Float16)c;
      }
}

// ---- K2: S[b,i,j] = max_f sum_h Y_f[i,h] Y_f[j,h]; S symmetric ----
// 288 blocks (8 b x 36 upper-tri tiles) x 512 thr. b = id & 7 XCD pin.
// Mirror block via LDS transpose (stride-129 fp32). Scalar LDS ptrs only.

__global__ __launch_bounds__(512, 4) void score_kernel(const _Float16* __restrict__ y_t,
                                                       float* __restrict__ S) {
  __shared__ __align__(16) char smem[128 * 129 * 4];   // 66048 B >= 4x16384 staging
  _Float16* LA0 = (_Float16*)smem;
  _Float16* LA1 = (_Float16*)(smem + 16384);
  _Float16* LB0 = (_Float16*)(smem + 32768);
  _Float16* LB1 = (_Float16*)(smem + 49152);
  int id = blockIdx.x;
  int b = id & 7;
  int tt = id >> 3;            // 0..35 upper-tri tile index
  int ti = 0;
  while (tt >= 8 - ti) { tt -= 8 - ti; ++ti; }
  int tj = ti + tt;
  int i0 = ti * 128, j0 = tj * 128;
  int t = threadIdx.x, lane = t & 63, w = t >> 6;
  int wm = w >> 2, wn = w & 3, quad = lane >> 4, l16 = lane & 15;
  const int PLANE = 1024 * 512;
  const _Float16* base = y_t + (size_t)b * 4 * PLANE;
  const _Float16* gpA[2]; const _Float16* gpB[2];
  init_ptrs<2, 512>(base, i0, 512, gpA);
  init_ptrs<2, 512>(base, j0, 512, gpB);
  floatx4 acc[4][2], smax[4][2];
  ZERO_ACC42(acc);
  stage<2, 512>(gpA, LA0); bump<2>(gpA, 64);
  stage<2, 512>(gpB, LB0); bump<2>(gpB, 64);
#pragma unroll 1
  for (int f = 0; f < 4; ++f) {
#pragma unroll 1
    for (int kt = 0; kt < 8; ++kt) {
      __syncthreads();
      if (f * 8 + kt < 31) {
        if (kt == 7) { bump<2>(gpA, PLANE - 512); bump<2>(gpB, PLANE - 512); }
        stage<2, 512>(gpA, ((kt + 1) & 1) ? LA1 : LA0); bump<2>(gpA, 64);
        stage<2, 512>(gpB, ((kt + 1) & 1) ? LB1 : LB0); bump<2>(gpB, 64);
      }
      mfma_tile42((kt & 1) ? LA1 : LA0, (kt & 1) ? LB1 : LB0, acc, wm, wn, l16, quad);
    }
    if (f == 0) {
#pragma unroll
      for (int mi = 0; mi < 4; ++mi)
#pragma unroll
        for (int ni = 0; ni < 2; ++ni) smax[mi][ni] = acc[mi][ni];
    } else {
#pragma unroll
      for (int mi = 0; mi < 4; ++mi)
#pragma unroll
        for (int ni = 0; ni < 2; ++ni)
#pragma unroll
          for (int r = 0; r < 4; ++r)
            smax[mi][ni][r] = fmaxf(smax[mi][ni][r], acc[mi][ni][r]);
    }
    ZERO_ACC42(acc);
  }
  float* Sb = S + (size_t)b * 1024 * 1024;
#pragma unroll
  for (int mi = 0; mi < 4; ++mi)
#pragma unroll
    for (int ni = 0; ni < 2; ++ni)
#pragma unroll
      for (int r = 0; r < 4; ++r) {
        int gi = i0 + wm * 64 + mi * 16 + quad * 4 + r;
        int gj = j0 + wn * 32 + ni * 16 + l16;
        Sb[(size_t)gi * 1024 + gj] = smax[mi][ni][r];
      }
  if (ti != tj) {
    __syncthreads();                 // staging buffers dead
    float* tl = (float*)smem;        // [128][129]
#pragma unroll
    for (int mi = 0; mi < 4; ++mi)
#pragma unroll
      for (int ni = 0; ni < 2; ++ni)
#pragma unroll
        for (int r = 0; r < 4; ++r)
          tl[(wm * 64 + mi * 16 + quad * 4 + r) * 129 + (wn * 32 + ni * 16 + l16)] =
              smax[mi][ni][r];
    __syncthreads();
#pragma unroll 1
    for (int k = 0; k < 32; ++k) {
      int flat = k * 512 + t;
      int rm = flat >> 7, cm = flat & 127;
      Sb[(size_t)(j0 + rm) * 1024 + (i0 + cm)] = tl[cm * 129 + rm];
    }
  }
}

// ---- K3: allennlp masked softmax per row -> alpha fp16 ----

__global__ __launch_bounds__(256) void softmax_kernel(const float* __restrict__ S,
                                                      const int* __restrict__ xmask,
                                                      _Float16* __restrict__ alpha) {
  __shared__ float red[16];
  int row = blockIdx.x;               // 0..8191
  int b = row >> 10, l = row & 1023;
  const float* sr = S + (size_t)row * 1024;
  const int* mr = xmask + b * 1024;
  int t = threadIdx.x, lane = t & 63, wid = t >> 6;
  int rm = mr[l];
  float v[4], mm[4];
  float vmax = 0.0f;
#pragma unroll
  for (int q = 0; q < 4; ++q) {
    int i = t + q * 256;
    int m = (rm && mr[i] && (i != l)) ? 1 : 0;
    mm[q] = (float)m;
    v[q] = m ? sr[i] : 0.0f;
    vmax = fmaxf(vmax, v[q]);
  }
  for (int off = 32; off; off >>= 1) vmax = fmaxf(vmax, __shfl_down(vmax, off));
  if (lane == 0) red[wid] = vmax;
  __syncthreads();
  if (t == 0) red[8] = fmaxf(fmaxf(red[0], red[1]), fmaxf(red[2], red[3]));
  __syncthreads();
  vmax = red[8];
  float e[4], E = 0.0f, E2 = 0.0f;
#pragma unroll
  for (int q = 0; q < 4; ++q) {
    e[q] = expf(v[q] - vmax);
    E += e[q];
    E2 += e[q] * mm[q];
  }
  for (int off = 32; off; off >>= 1) {
    E += __shfl_down(E, off);
    E2 += __shfl_down(E2, off);
  }
  if (lane == 0) { red[wid] = E; red[4 + wid] = E2; }
  __syncthreads();
  if (t == 0) {
    red[9] = red[0] + red[1] + red[2] + red[3];
    red[10] = red[4] + red[5] + red[6] + red[7];
  }
  __syncthreads();
  E = red[9]; E2 = red[10];
  float inv = 1.0f / (E2 + 1e-13f * E);
  _Float16* ar = alpha + (size_t)row * 1024;
#pragma unroll
  for (int q = 0; q < 4; ++q) {
    int i = t + q * 256;
    ar[i] = (_Float16)(e[q] * mm[q] * inv);
  }
}

// ---- K4: enc[b] = alpha[b] @ x[b]  (xT (B,H,L) as B-operand) ----
// 512 blocks x 256 thr: 64-row i-tiles x 4 n-tiles x 8 b; b = id & 7 XCD pin.

__global__ __launch_bounds__(256) void attn_kernel(const _Float16* __restrict__ alpha,
                                                   const _Float16* __restrict__ xT,
                                                   _Float16* __restrict__ enc) {
  __shared__ __align__(16) _Float16 ldsA[2][64 * 64];
  __shared__ __align__(16) _Float16 ldsB[2][128 * 64];
  int id = blockIdx.x;
  int b = id & 7;
  int r2 = id >> 3;                 // 0..63
  int i0 = (r2 >> 2) * 64;
  int n0 = (r2 & 3) * 128;
  const _Float16* A = alpha + (size_t)b * 1024 * 1024;
  const _Float16* Bm = xT + (size_t)b * 512 * 1024;
  int t = threadIdx.x, lane = t & 63, wn = t >> 6;   // wave grid 1x4
  int quad = lane >> 4, l16 = lane & 15;
  const _Float16* gpA[2]; const _Float16* gpB[4];
  init_ptrs<2, 256>(A, i0, 1024, gpA);
  init_ptrs<4, 256>(Bm, n0, 1024, gpB);
  floatx4 acc[4][2];
  ZERO_ACC42(acc);
  stage<2, 256>(gpA, ldsA[0]); bump<2>(gpA, 64);
  stage<4, 256>(gpB, ldsB[0]); bump<4>(gpB, 64);
#pragma unroll 1
  for (int kt = 0; kt < 16; ++kt) {
    __syncthreads();
    if (kt < 15) {
      stage<2, 256>(gpA, ldsA[(kt + 1) & 1]); bump<2>(gpA, 64);
      stage<4, 256>(gpB, ldsB[(kt + 1) & 1]); bump<4>(gpB, 64);
    }
    const _Float16* la = ldsA[kt & 1];
    const _Float16* lb = ldsB[kt & 1];
#pragma unroll
    for (int kf = 0; kf < 2; ++kf) {
      half8 af[4], bf[2];
#pragma unroll
      for (int i = 0; i < 4; ++i) af[i] = frag_ld(la, i * 16 + l16, kf * 4 + quad);
#pragma unroll
      for (int i = 0; i < 2; ++i) bf[i] = frag_ld(lb, wn * 32 + i * 16 + l16, kf * 4 + quad);
#pragma unroll
      for (int mi = 0; mi < 4; ++mi)
#pragma unroll
        for (int ni = 0; ni < 2; ++ni)
          acc[mi][ni] = __builtin_amdgcn_mfma_f32_16x16x32_f16(af[mi], bf[ni], acc[mi][ni], 0, 0, 0);
    }
  }
  _Float16* eb = enc + (size_t)b * 1024 * 512;
#pragma unroll
  for (int mi = 0; mi < 4; ++mi)
#pragma unroll
    for (int ni = 0; ni < 2; ++ni)
#pragma unroll
      for (int r = 0; r < 4; ++r) {
        int gr = i0 + mi * 16 + quad * 4 + r;
        int gc = n0 + wn * 32 + ni * 16 + l16;
        eb[(size_t)gr * 512 + gc] = (_Float16)acc[mi][ni][r];
      }
}

// ---- K5: gate = sigmoid([x|enc] @ W_gate + b_gate); out = gate*[x16|enc] ----
// 256 thr, 2x2 waves, dbuf BK=32 (32 KB LDS -> 5 blocks/CU, 20 waves/CU).
// grid (64,8): i0 on x for XCD L2 locality. K=1024 -> 32 steps.

__global__ __launch_bounds__(256) void gate_kernel(const _Float16* __restrict__ x16,
                                                   const _Float16* __restrict__ enc,
                                                   const _Float16* __restrict__ WgT,
                                                   const float* __restrict__ bg,
                                                   float* __restrict__ out) {
  __shared__ __align__(16) _Float16 ldsA[2][128 * 32];
  __shared__ __align__(16) _Float16 ldsB[2][128 * 32];
  int i0 = blockIdx.x * 128, n0 = blockIdx.y * 128;
  int t = threadIdx.x, lane = t & 63, w = t >> 6;
  int wm = w >> 1, wn = w & 1, quad = lane >> 4, l16 = lane & 15;
  const _Float16* gpA[2]; const _Float16* gpA2[2]; const _Float16* gpB[2];
  init_ptrs32<2, 256>(x16, i0, 512, gpA);
  init_ptrs32<2, 256>(enc, i0, 512, gpA2);
  init_ptrs32<2, 256>(WgT, n0, 1024, gpB);
  floatx4 acc[4][4];
  ZERO_ACC44(acc);
  stage<2, 256>(gpA, ldsA[0]); bump<2>(gpA, 32);
  stage<2, 256>(gpB, ldsB[0]); bump<2>(gpB, 32);
  // A prefetch for step kt+1: kt<15 -> x16 tile kt+1; kt=15..30 -> enc tile kt-15.
#pragma unroll 1
  for (int kt = 0; kt < 32; ++kt) {
    __syncthreads();
    if (kt < 31) {
      if (kt < 15) { stage<2, 256>(gpA,  ldsA[(kt + 1) & 1]); bump<2>(gpA, 32); }
      else         { stage<2, 256>(gpA2, ldsA[(kt + 1) & 1]); bump<2>(gpA2, 32); }
      stage<2, 256>(gpB, ldsB[(kt + 1) & 1]); bump<2>(gpB, 32);
    }
    mfma_tile44_32(ldsA[kt & 1], ldsB[kt & 1], acc, wm, wn, l16, quad);
  }
#pragma unroll
  for (int mi = 0; mi < 4; ++mi)
#pragma unroll
    for (int ni = 0; ni < 4; ++ni)
#pragma unroll
      for (int r = 0; r < 4; ++r) {
        int gr = i0 + wm * 64 + mi * 16 + quad * 4 + r;  // 0..8191
        int gc = n0 + wn * 64 + ni * 16 + l16;           // 0..1023
        float c = acc[mi][ni][r] + bg[gc];
        float g = 1.0f / (1.0f + expf(-c));
        float jv = (gc < 512) ? (float)x16[(size_t)gr * 512 + gc]
                              : (float)enc[(size_t)gr * 512 + (gc - 512)];
        out[(size_t)gr * 1024 + gc] = g * jv;
      }
}

// ---- launch ----

extern "C" void kernel_launch(void* const* d_in, const int* in_sizes, int n_in,
                              void* d_out, int out_size, void* d_ws, size_t ws_size,
                              hipStream_t stream) {
  const float* x  = (const float*)d_in[0];   // (8,1024,512)
  const int* xm   = (const int*)d_in[1];     // (8,1024)
  const float* Wp = (const float*)d_in[2];   // (512,2048)
  const float* bp = (const float*)d_in[3];   // (2048)
  const float* Wg = (const float*)d_in[4];   // (1024,1024)
  const float* bg = (const float*)d_in[5];   // (1024)
  float* out = (float*)d_out;

  char* ws = (char*)d_ws;
  const size_t MB = 1024 * 1024;
  _Float16* x16 = (_Float16*)(ws);            // 8 MB  (8192,512)
  _Float16* xT  = (_Float16*)(ws + 8 * MB);   // 8 MB  (8,512,1024)
  _Float16* WpT = (_Float16*)(ws + 16 * MB);  // 2 MB  (2048,512)
  _Float16* WgT = (_Float16*)(ws + 18 * MB);  // 2 MB  (1024,1024)
  _Float16* y_t = (_Float16*)(ws + 20 * MB);  // 32 MB (8,4,1024,512)
  float*    S   = (float*)(ws + 52 * MB);     // 32 MB (8,1024,1024)  [end: 84 MB]
  // y_t is dead after score_kernel: alias alpha/enc onto it
  _Float16* alpha = (_Float16*)(ws + 20 * MB); // 16 MB (8,1024,1024)
  _Float16* enc   = (_Float16*)(ws + 36 * MB); // 8 MB  (8,1024,512)

  x_prep_kernel<<<dim3(16, 32, 8), 256, 0, stream>>>(x, x16, xT);
  w_prep_kernel<<<dim3(64, 16, 2), 256, 0, stream>>>(Wp, WpT, Wg, WgT);

  proj_kernel<<<dim3(64, 16), 256, 0, stream>>>(x16, WpT, bp, y_t);
  score_kernel<<<288, 512, 0, stream>>>(y_t, S);
  softmax_kernel<<<8192, 256, 0, stream>>>(S, xm, alpha);
  attn_kernel<<<512, 256, 0, stream>>>(alpha, xT, enc);
  gate_kernel<<<dim3(64, 8), 256, 0, stream>>>(x16, enc, WgT, bg, out);
}

// Round 12
// 205.071 us; speedup vs baseline: 1.0897x; 1.0897x over previous
//
#include <hip/hip_runtime.h>

// Problem constants: B=8, L=1024, H=512, F=4
// out = gate * [x | alpha @ x],  gate = sigmoid([x|enc] @ W_gate)
// alpha = masked_softmax(max_f(Y_f Y_f^T)),  Y = relu(x @ W_proj)
//
// Round 12: (1) revert proj/gate to BK=64 (r11's BK=32 hit 2M 4-way LDS bank
// conflicts: 64B row stride aliases rows r/r+2; XOR by row&3 collides rows
// 0,4,8,12). (2) WpT rows pre-permuted so proj's output column is f*512+h
// (was h*4+f): epilogue stores become 32B-contiguous per quad instead of
// 16 scattered 8B pieces per instr (proj epilogue = 64 scalar 2B stores/thr
// across 4 planes was the hidden store-transaction bottleneck).

typedef _Float16 half8 __attribute__((ext_vector_type(8)));
typedef float floatx4 __attribute__((ext_vector_type(4)));

typedef const __attribute__((address_space(1))) void* gas_ptr;
typedef __attribute__((address_space(3))) void* las_ptr;

// ---- staging machinery: BK=64 rows (64 fp16/row), XOR-swizzle by row&7 ----
// Chunk c covers row=c>>3, group kg=c&7, global col (kg^(row&7))*8; LDS dst =
// c*16 B (wave-uniform base + lane*16 contract of global_load_lds). Row
// stride 128 B = 32 banks -> rows never alias; swizzle makes frag reads clean.

template<int NCH, int NT>
__device__ __forceinline__ void init_ptrs(const _Float16* src, int row0, int ld,
                                          const _Float16* gp[NCH]) {
  int t = threadIdx.x;
#pragma unroll
  for (int p = 0; p < NCH; ++p) {
    int c = p * NT + t;
    int row = c >> 3;
    int kg = c & 7;
    int gk = (kg ^ (row & 7)) << 3;
    gp[p] = src + (size_t)(row0 + row) * ld + gk;
  }
}

template<int NCH, int NT>
__device__ __forceinline__ void stage(const _Float16* const gp[NCH], _Float16* ldsbuf) {
  int t = threadIdx.x;
#pragma unroll
  for (int p = 0; p < NCH; ++p)
    __builtin_amdgcn_global_load_lds((gas_ptr)gp[p],
                                     (las_ptr)(ldsbuf + t * 8 + p * NT * 8), 16, 0, 0);
}

template<int NCH>
__device__ __forceinline__ void bump(const _Float16* gp[NCH], int d) {
#pragma unroll
  for (int p = 0; p < NCH; ++p) gp[p] += d;
}

__device__ __forceinline__ half8 frag_ld(const _Float16* lds, int row, int g) {
  return *(const half8*)(lds + row * 64 + ((g ^ (row & 7)) << 3));
}

// 4-wave (2x2) block: wave tile 64x64, per-lane acc 4x4
__device__ __forceinline__ void mfma_tile44(const _Float16* lds_a, const _Float16* lds_b,
                                            floatx4 acc[4][4], int wm, int wn,
                                            int l16, int quad) {
#pragma unroll
  for (int kf = 0; kf < 2; ++kf) {
    half8 af[4], bf[4];
#pragma unroll
    for (int i = 0; i < 4; ++i) af[i] = frag_ld(lds_a, wm * 64 + i * 16 + l16, kf * 4 + quad);
#pragma unroll
    for (int i = 0; i < 4; ++i) bf[i] = frag_ld(lds_b, wn * 64 + i * 16 + l16, kf * 4 + quad);
#pragma unroll
    for (int mi = 0; mi < 4; ++mi)
#pragma unroll
      for (int ni = 0; ni < 4; ++ni)
        acc[mi][ni] = __builtin_amdgcn_mfma_f32_16x16x32_f16(af[mi], bf[ni], acc[mi][ni], 0, 0, 0);
  }
}

#define ZERO_ACC44(acc)                                 \
  _Pragma("unroll") for (int mi = 0; mi < 4; ++mi)      \
  _Pragma("unroll") for (int ni = 0; ni < 4; ++ni)      \
  _Pragma("unroll") for (int r = 0; r < 4; ++r) acc[mi][ni][r] = 0.0f;

// 8-wave (2x4) block: wave tile 64x32, per-lane acc 4x2 (score)
__device__ __forceinline__ void mfma_tile42(const _Float16* la, const _Float16* lb,
                                            floatx4 acc[4][2], int wm, int wn,
                                            int l16, int quad) {
#pragma unroll
  for (int kf = 0; kf < 2; ++kf) {
    half8 af[4], bf[2];
#pragma unroll
    for (int i = 0; i < 4; ++i) af[i] = frag_ld(la, wm * 64 + i * 16 + l16, kf * 4 + quad);
#pragma unroll
    for (int i = 0; i < 2; ++i) bf[i] = frag_ld(lb, wn * 32 + i * 16 + l16, kf * 4 + quad);
#pragma unroll
    for (int mi = 0; mi < 4; ++mi)
#pragma unroll
      for (int ni = 0; ni < 2; ++ni)
        acc[mi][ni] = __builtin_amdgcn_mfma_f32_16x16x32_f16(af[mi], bf[ni], acc[mi][ni], 0, 0, 0);
  }
}

#define ZERO_ACC42(acc)                                 \
  _Pragma("unroll") for (int mi = 0; mi < 4; ++mi)      \
  _Pragma("unroll") for (int ni = 0; ni < 2; ++ni)      \
  _Pragma("unroll") for (int r = 0; r < 4; ++r) acc[mi][ni][r] = 0.0f;

// ---- pre-pass ----

__global__ void x_prep_kernel(const float* __restrict__ in, _Float16* __restrict__ x16,
                              _Float16* __restrict__ xT) {
  __shared__ float tile[32][33];
  const int R = 1024, C = 512;
  int c0 = blockIdx.x * 32, r0 = blockIdx.y * 32;
  size_t boff = (size_t)blockIdx.z * R * C;
  in += boff; x16 += boff; xT += boff;
  int tx = threadIdx.x & 31, ty = threadIdx.x >> 5;  // 32 x 8
#pragma unroll
  for (int i = 0; i < 32; i += 8) {
    float v = in[(size_t)(r0 + ty + i) * C + c0 + tx];
    tile[ty + i][tx] = v;
    x16[(size_t)(r0 + ty + i) * C + c0 + tx] = (_Float16)v;
  }
  __syncthreads();
#pragma unroll
  for (int i = 0; i < 32; i += 8)
    xT[(size_t)(c0 + ty + i) * R + r0 + tx] = (_Float16)tile[tx][ty + i];
}

// z=0: Wp (512,2048) -> WpT' (2048,512) with ROW PERMUTATION: orig column
//      k = h*4+f lands at row f*512+h, so proj's output col n = f*512+h.
// z=1: Wg (1024,1024) -> WgT (1024,1024), plain transpose.
__global__ void w_prep_kernel(const float* __restrict__ Wp, _Float16* __restrict__ WpT,
                              const float* __restrict__ Wg, _Float16* __restrict__ WgT) {
  __shared__ float tile[32][33];
  const float* in; _Float16* out; int R, C, c0, r0;
  if (blockIdx.z == 0) {
    in = Wp; out = WpT; R = 512; C = 2048;
    c0 = blockIdx.x * 32; r0 = blockIdx.y * 32;
  } else {
    in = Wg; out = WgT; R = 1024; C = 1024;
    c0 = (blockIdx.x & 31) * 32; r0 = (blockIdx.y * 2 + (blockIdx.x >> 5)) * 32;
  }
  int tx = threadIdx.x & 31, ty = threadIdx.x >> 5;
#pragma unroll
  for (int i = 0; i < 32; i += 8)
    tile[ty + i][tx] = in[(size_t)(r0 + ty + i) * C + c0 + tx];
  __syncthreads();
#pragma unroll
  for (int i = 0; i < 32; i += 8) {
    int rr = c0 + ty + i;            // original column index of `in`
    int prow = (blockIdx.z == 0) ? ((rr & 3) * 512 + (rr >> 2)) : rr;
    out[(size_t)prow * R + r0 + tx] = (_Float16)tile[tx][ty + i];
  }
}

// ---- K1: y = relu(x @ W_proj + b_proj) -> y_t (B,F,L,H) fp16 ----
// 256 thr, 2x2 waves, 128x128 tile, dbuf BK=64. Output col n = f*512+h
// (WpT pre-permuted) -> stores are 32B-contiguous per quad, one plane.

__global__ __launch_bounds__(256) void proj_kernel(const _Float16* __restrict__ x16,
                                                   const _Float16* __restrict__ WpT,
                                                   const float* __restrict__ bp,
                                                   _Float16* __restrict__ y_t) {
  __shared__ __align__(16) _Float16 ldsA[2][128 * 64];
  __shared__ __align__(16) _Float16 ldsB[2][128 * 64];
  int i0 = blockIdx.x * 128, n0 = blockIdx.y * 128;
  int t = threadIdx.x, lane = t & 63, w = t >> 6;
  int wm = w >> 1, wn = w & 1, quad = lane >> 4, l16 = lane & 15;
  const _Float16* gpA[4]; const _Float16* gpB[4];
  init_ptrs<4, 256>(x16, i0, 512, gpA);
  init_ptrs<4, 256>(WpT, n0, 512, gpB);
  floatx4 acc[4][4];
  ZERO_ACC44(acc);
  stage<4, 256>(gpA, ldsA[0]); bump<4>(gpA, 64);
  stage<4, 256>(gpB, ldsB[0]); bump<4>(gpB, 64);
#pragma unroll 1
  for (int kt = 0; kt < 8; ++kt) {
    __syncthreads();
    if (kt < 7) {
      stage<4, 256>(gpA, ldsA[(kt + 1) & 1]); bump<4>(gpA, 64);
      stage<4, 256>(gpB, ldsB[(kt + 1) & 1]); bump<4>(gpB, 64);
    }
    mfma_tile44(ldsA[kt & 1], ldsB[kt & 1], acc, wm, wn, l16, quad);
  }
#pragma unroll
  for (int mi = 0; mi < 4; ++mi)
#pragma unroll
    for (int ni = 0; ni < 4; ++ni)
#pragma unroll
      for (int r = 0; r < 4; ++r) {
        int gr = i0 + wm * 64 + mi * 16 + quad * 4 + r;   // 0..8191
        int gc = n0 + wn * 64 + ni * 16 + l16;            // permuted col f*512+h
        int f = gc >> 9, h = gc & 511;
        float c = fmaxf(acc[mi][ni][r] + bp[h * 4 + f], 0.0f);
        int b = gr >> 10, l = gr & 1023;
        y_t[(((size_t)(b * 4 + f)) * 1024 + l) * 512 + h] = (_Float16)c;
      }
}

// ---- K2: S[b,i,j] = max_f sum_h Y_f[i,h] Y_f[j,h]; S symmetric ----
// 288 blocks (8 b x 36 upper-tri tiles) x 512 thr. b = id & 7 XCD pin.
// Mirror block via LDS transpose (stride-129 fp32). Scalar LDS ptrs only.

__global__ __launch_bounds__(512, 4) void score_kernel(const _Float16* __restrict__ y_t,
                                                       float* __restrict__ S) {
  __shared__ __align__(16) char smem[128 * 129 * 4];   // 66048 B >= 4x16384 staging
  _Float16* LA0 = (_Float16*)smem;
  _Float16* LA1 = (_Float16*)(smem + 16384);
  _Float16* LB0 = (_Float16*)(smem + 32768);
  _Float16* LB1 = (_Float16*)(smem + 49152);
  int id = blockIdx.x;
  int b = id & 7;
  int tt = id >> 3;            // 0..35 upper-tri tile index
  int ti = 0;
  while (tt >= 8 - ti) { tt -= 8 - ti; ++ti; }
  int tj = ti + tt;
  int i0 = ti * 128, j0 = tj * 128;
  int t = threadIdx.x, lane = t & 63, w = t >> 6;
  int wm = w >> 2, wn = w & 3, quad = lane >> 4, l16 = lane & 15;
  const int PLANE = 1024 * 512;
  const _Float16* base = y_t + (size_t)b * 4 * PLANE;
  const _Float16* gpA[2]; const _Float16* gpB[2];
  init_ptrs<2, 512>(base, i0, 512, gpA);
  init_ptrs<2, 512>(base, j0, 512, gpB);
  floatx4 acc[4][2], smax[4][2];
  ZERO_ACC42(acc);
  stage<2, 512>(gpA, LA0); bump<2>(gpA, 64);
  stage<2, 512>(gpB, LB0); bump<2>(gpB, 64);
#pragma unroll 1
  for (int f = 0; f < 4; ++f) {
#pragma unroll 1
    for (int kt = 0; kt < 8; ++kt) {
      __syncthreads();
      if (f * 8 + kt < 31) {
        if (kt == 7) { bump<2>(gpA, PLANE - 512); bump<2>(gpB, PLANE - 512); }
        stage<2, 512>(gpA, ((kt + 1) & 1) ? LA1 : LA0); bump<2>(gpA, 64);
        stage<2, 512>(gpB, ((kt + 1) & 1) ? LB1 : LB0); bump<2>(gpB, 64);
      }
      mfma_tile42((kt & 1) ? LA1 : LA0, (kt & 1) ? LB1 : LB0, acc, wm, wn, l16, quad);
    }
    if (f == 0) {
#pragma unroll
      for (int mi = 0; mi < 4; ++mi)
#pragma unroll
        for (int ni = 0; ni < 2; ++ni) smax[mi][ni] = acc[mi][ni];
    } else {
#pragma unroll
      for (int mi = 0; mi < 4; ++mi)
#pragma unroll
        for (int ni = 0; ni < 2; ++ni)
#pragma unroll
          for (int r = 0; r < 4; ++r)
            smax[mi][ni][r] = fmaxf(smax[mi][ni][r], acc[mi][ni][r]);
    }
    ZERO_ACC42(acc);
  }
  float* Sb = S + (size_t)b * 1024 * 1024;
#pragma unroll
  for (int mi = 0; mi < 4; ++mi)
#pragma unroll
    for (int ni = 0; ni < 2; ++ni)
#pragma unroll
      for (int r = 0; r < 4; ++r) {
        int gi = i0 + wm * 64 + mi * 16 + quad * 4 + r;
        int gj = j0 + wn * 32 + ni * 16 + l16;
        Sb[(size_t)gi * 1024 + gj] = smax[mi][ni][r];
      }
  if (ti != tj) {
    __syncthreads();                 // staging buffers dead
    float* tl = (float*)smem;        // [128][129]
#pragma unroll
    for (int mi = 0; mi < 4; ++mi)
#pragma unroll
      for (int ni = 0; ni < 2; ++ni)
#pragma unroll
        for (int r = 0; r < 4; ++r)
          tl[(wm * 64 + mi * 16 + quad * 4 + r) * 129 + (wn * 32 + ni * 16 + l16)] =
              smax[mi][ni][r];
    __syncthreads();
#pragma unroll 1
    for (int k = 0; k < 32; ++k) {
      int flat = k * 512 + t;
      int rm = flat >> 7, cm = flat & 127;
      Sb[(size_t)(j0 + rm) * 1024 + (i0 + cm)] = tl[cm * 129 + rm];
    }
  }
}

// ---- K3: allennlp masked softmax per row -> alpha fp16 ----

__global__ __launch_bounds__(256) void softmax_kernel(const float* __restrict__ S,
                                                      const int* __restrict__ xmask,
                                                      _Float16* __restrict__ alpha) {
  __shared__ float red[16];
  int row = blockIdx.x;               // 0..8191
  int b = row >> 10, l = row & 1023;
  const float* sr = S + (size_t)row * 1024;
  const int* mr = xmask + b * 1024;
  int t = threadIdx.x, lane = t & 63, wid = t >> 6;
  int rm = mr[l];
  float v[4], mm[4];
  float vmax = 0.0f;
#pragma unroll
  for (int q = 0; q < 4; ++q) {
    int i = t + q * 256;
    int m = (rm && mr[i] && (i != l)) ? 1 : 0;
    mm[q] = (float)m;
    v[q] = m ? sr[i] : 0.0f;
    vmax = fmaxf(vmax, v[q]);
  }
  for (int off = 32; off; off >>= 1) vmax = fmaxf(vmax, __shfl_down(vmax, off));
  if (lane == 0) red[wid] = vmax;
  __syncthreads();
  if (t == 0) red[8] = fmaxf(fmaxf(red[0], red[1]), fmaxf(red[2], red[3]));
  __syncthreads();
  vmax = red[8];
  float e[4], E = 0.0f, E2 = 0.0f;
#pragma unroll
  for (int q = 0; q < 4; ++q) {
    e[q] = expf(v[q] - vmax);
    E += e[q];
    E2 += e[q] * mm[q];
  }
  for (int off = 32; off; off >>= 1) {
    E += __shfl_down(E, off);
    E2 += __shfl_down(E2, off);
  }
  if (lane == 0) { red[wid] = E; red[4 + wid] = E2; }
  __syncthreads();
  if (t == 0) {
    red[9] = red[0] + red[1] + red[2] + red[3];
    red[10] = red[4] + red[5] + red[6] + red[7];
  }
  __syncthreads();
  E = red[9]; E2 = red[10];
  float inv = 1.0f / (E2 + 1e-13f * E);
  _Float16* ar = alpha + (size_t)row * 1024;
#pragma unroll
  for (int q = 0; q < 4; ++q) {
    int i = t + q * 256;
    ar[i] = (_Float16)(e[q] * mm[q] * inv);
  }
}

// ---- K4: enc[b] = alpha[b] @ x[b]  (xT (B,H,L) as B-operand) ----
// 512 blocks x 256 thr: 64-row i-tiles x 4 n-tiles x 8 b; b = id & 7 XCD pin.

__global__ __launch_bounds__(256) void attn_kernel(const _Float16* __restrict__ alpha,
                                                   const _Float16* __restrict__ xT,
                                                   _Float16* __restrict__ enc) {
  __shared__ __align__(16) _Float16 ldsA[2][64 * 64];
  __shared__ __align__(16) _Float16 ldsB[2][128 * 64];
  int id = blockIdx.x;
  int b = id & 7;
  int r2 = id >> 3;                 // 0..63
  int i0 = (r2 >> 2) * 64;
  int n0 = (r2 & 3) * 128;
  const _Float16* A = alpha + (size_t)b * 1024 * 1024;
  const _Float16* Bm = xT + (size_t)b * 512 * 1024;
  int t = threadIdx.x, lane = t & 63, wn = t >> 6;   // wave grid 1x4
  int quad = lane >> 4, l16 = lane & 15;
  const _Float16* gpA[2]; const _Float16* gpB[4];
  init_ptrs<2, 256>(A, i0, 1024, gpA);
  init_ptrs<4, 256>(Bm, n0, 1024, gpB);
  floatx4 acc[4][2];
  ZERO_ACC42(acc);
  stage<2, 256>(gpA, ldsA[0]); bump<2>(gpA, 64);
  stage<4, 256>(gpB, ldsB[0]); bump<4>(gpB, 64);
#pragma unroll 1
  for (int kt = 0; kt < 16; ++kt) {
    __syncthreads();
    if (kt < 15) {
      stage<2, 256>(gpA, ldsA[(kt + 1) & 1]); bump<2>(gpA, 64);
      stage<4, 256>(gpB, ldsB[(kt + 1) & 1]); bump<4>(gpB, 64);
    }
    const _Float16* la = ldsA[kt & 1];
    const _Float16* lb = ldsB[kt & 1];
#pragma unroll
    for (int kf = 0; kf < 2; ++kf) {
      half8 af[4], bf[2];
#pragma unroll
      for (int i = 0; i < 4; ++i) af[i] = frag_ld(la, i * 16 + l16, kf * 4 + quad);
#pragma unroll
      for (int i = 0; i < 2; ++i) bf[i] = frag_ld(lb, wn * 32 + i * 16 + l16, kf * 4 + quad);
#pragma unroll
      for (int mi = 0; mi < 4; ++mi)
#pragma unroll
        for (int ni = 0; ni < 2; ++ni)
          acc[mi][ni] = __builtin_amdgcn_mfma_f32_16x16x32_f16(af[mi], bf[ni], acc[mi][ni], 0, 0, 0);
    }
  }
  _Float16* eb = enc + (size_t)b * 1024 * 512;
#pragma unroll
  for (int mi = 0; mi < 4; ++mi)
#pragma unroll
    for (int ni = 0; ni < 2; ++ni)
#pragma unroll
      for (int r = 0; r < 4; ++r) {
        int gr = i0 + mi * 16 + quad * 4 + r;
        int gc = n0 + wn * 32 + ni * 16 + l16;
        eb[(size_t)gr * 512 + gc] = (_Float16)acc[mi][ni][r];
      }
}

// ---- K5: gate = sigmoid([x|enc] @ W_gate + b_gate); out = gate*[x16|enc] ----
// 256 thr, 2x2 waves, dbuf BK=64 (r10-proven). grid (64,8).

__global__ __launch_bounds__(256) void gate_kernel(const _Float16* __restrict__ x16,
                                                   const _Float16* __restrict__ enc,
                                                   const _Float16* __restrict__ WgT,
                                                   const float* __restrict__ bg,
                                                   float* __restrict__ out) {
  __shared__ __align__(16) _Float16 ldsA[2][128 * 64];
  __shared__ __align__(16) _Float16 ldsB[2][128 * 64];
  int i0 = blockIdx.x * 128, n0 = blockIdx.y * 128;
  int t = threadIdx.x, lane = t & 63, w = t >> 6;
  int wm = w >> 1, wn = w & 1, quad = lane >> 4, l16 = lane & 15;
  const _Float16* gpA[4]; const _Float16* gpA2[4]; const _Float16* gpB[4];
  init_ptrs<4, 256>(x16, i0, 512, gpA);
  init_ptrs<4, 256>(enc, i0, 512, gpA2);
  init_ptrs<4, 256>(WgT, n0, 1024, gpB);
  floatx4 acc[4][4];
  ZERO_ACC44(acc);
  stage<4, 256>(gpA, ldsA[0]); bump<4>(gpA, 64);
  stage<4, 256>(gpB, ldsB[0]); bump<4>(gpB, 64);
#pragma unroll 1
  for (int kt = 0; kt < 16; ++kt) {
    __syncthreads();
    if (kt < 15) {
      if (kt < 7) { stage<4, 256>(gpA,  ldsA[(kt + 1) & 1]); bump<4>(gpA, 64); }
      else        { stage<4, 256>(gpA2, ldsA[(kt + 1) & 1]); bump<4>(gpA2, 64); }
      stage<4, 256>(gpB, ldsB[(kt + 1) & 1]); bump<4>(gpB, 64);
    }
    mfma_tile44(ldsA[kt & 1], ldsB[kt & 1], acc, wm, wn, l16, quad);
  }
#pragma unroll
  for (int mi = 0; mi < 4; ++mi)
#pragma unroll
    for (int ni = 0; ni < 4; ++ni)
#pragma unroll
      for (int r = 0; r < 4; ++r) {
        int gr = i0 + wm * 64 + mi * 16 + quad * 4 + r;  // 0..8191
        int gc = n0 + wn * 64 + ni * 16 + l16;           // 0..1023
        float c = acc[mi][ni][r] + bg[gc];
        float g = 1.0f / (1.0f + expf(-c));
        float jv = (gc < 512) ? (float)x16[(size_t)gr * 512 + gc]
                              : (float)enc[(size_t)gr * 512 + (gc - 512)];
        out[(size_t)gr * 1024 + gc] = g * jv;
      }
}

// ---- launch ----

extern "C" void kernel_launch(void* const* d_in, const int* in_sizes, int n_in,
                              void* d_out, int out_size, void* d_ws, size_t ws_size,
                              hipStream_t stream) {
  const float* x  = (const float*)d_in[0];   // (8,1024,512)
  const int* xm   = (const int*)d_in[1];     // (8,1024)
  const float* Wp = (const float*)d_in[2];   // (512,2048)
  const float* bp = (const float*)d_in[3];   // (2048)
  const float* Wg = (const float*)d_in[4];   // (1024,1024)
  const float* bg = (const float*)d_in[5];   // (1024)
  float* out = (float*)d_out;

  char* ws = (char*)d_ws;
  const size_t MB = 1024 * 1024;
  _Float16* x16 = (_Float16*)(ws);            // 8 MB  (8192,512)
  _Float16* xT  = (_Float16*)(ws + 8 * MB);   // 8 MB  (8,512,1024)
  _Float16* WpT = (_Float16*)(ws + 16 * MB);  // 2 MB  (2048,512) row-permuted
  _Float16* WgT = (_Float16*)(ws + 18 * MB);  // 2 MB  (1024,1024)
  _Float16* y_t = (_Float16*)(ws + 20 * MB);  // 32 MB (8,4,1024,512)
  float*    S   = (float*)(ws + 52 * MB);     // 32 MB (8,1024,1024)  [end: 84 MB]
  // y_t is dead after score_kernel: alias alpha/enc onto it
  _Float16* alpha = (_Float16*)(ws + 20 * MB); // 16 MB (8,1024,1024)
  _Float16* enc   = (_Float16*)(ws + 36 * MB); // 8 MB  (8,1024,512)

  x_prep_kernel<<<dim3(16, 32, 8), 256, 0, stream>>>(x, x16, xT);
  w_prep_kernel<<<dim3(64, 16, 2), 256, 0, stream>>>(Wp, WpT, Wg, WgT);

  proj_kernel<<<dim3(64, 16), 256, 0, stream>>>(x16, WpT, bp, y_t);
  score_kernel<<<288, 512, 0, stream>>>(y_t, S);
  softmax_kernel<<<8192, 256, 0, stream>>>(S, xm, alpha);
  attn_kernel<<<512, 256, 0, stream>>>(alpha, xT, enc);
  gate_kernel<<<dim3(64, 8), 256, 0, stream>>>(x16, enc, WgT, bg, out);
}